// Round 5
// baseline (113.857 us; speedup 1.0000x reference)
//
#include <hip/hip_runtime.h>
#include <stdint.h>
#include <stddef.h>

// SIR scan: B=16384 batches, T=2048 steps, F=2 (beta,gamma), fp32.
// Round 5: controlled experiment vs round 3 -- replace global_load_lds
// staging with REGISTER staging (global_load_dwordx4 -> VGPR -> ds_write).
// Theory: LDS-DMA has an in-order per-CU return path; one HBM-stalled
// line HoL-blocks younger returns, capping fill at ~7 B/cyc/CU (seen in
// R1-R4 regardless of pipeline structure). Register loads return out of
// order. Everything else (consumer wave, barrier protocol, swizzle,
// buffers) identical to round 3.

#define T_STEPS 2048
#define C_STEPS 64                   // timesteps per chunk
#define NCHUNK  (T_STEPS / C_STEPS)  // 32
#define BPB     64                   // batches per block
#define PAIRS   (C_STEPS / 2)        // 32 float4 slots per batch per chunk
#define NPROD   2                    // producer waves
#define RPP     (BPB / NPROD)        // 32 rows per producer
#define LPC     16                   // float4 loads per producer per chunk

#define INV_POP 1e-6f

// Load producer w's 16 KB slice of chunk c into regs (float4 r[LPC]).
// Instr k covers rows {2k, 2k+1} of the producer's 32-row group:
// lane l -> row RPP*w + 2k + (l>>5), slot q = l&31, global pair
// p = q ^ (row&15)  (swizzle carried on the global side, rule #21).
__device__ __forceinline__ void load_slice(const float* __restrict__ in,
                                           int b0, int c, int w, int lane,
                                           float4* r)
{
    const int hi = lane >> 5;
    const int q  = lane & 31;
#pragma unroll
    for (int k = 0; k < LPC; ++k) {
        const int row = RPP * w + 2 * k + hi;
        const int p   = q ^ (row & 15);
        const float4* g = (const float4*)(in
            + (size_t)(b0 + row) * (T_STEPS * 2)
            + (size_t)c * (C_STEPS * 2)) + p;
        r[k] = *g;
    }
}

// Write the slice to LDS: lane l writes its 16 B to [row][q] (linear);
// slot q of row holds global pair q^(row&15), matching the consumer read.
__device__ __forceinline__ void write_slice(float4* buf, int w, int lane,
                                            const float4* r)
{
    const int hi = lane >> 5;
    const int q  = lane & 31;
#pragma unroll
    for (int k = 0; k < LPC; ++k) {
        const int row = RPP * w + 2 * k + hi;
        buf[row * PAIRS + q] = r[k];
    }
}

// Consume one chunk: 32 ds_read_b128 per lane (XOR swizzle), 64 steps.
__device__ __forceinline__ void compute_chunk(const float4* lds, int tid,
                                              float& S, float& I, float& R)
{
    const int swz = tid & 15;
    const float4* row = lds + tid * PAIRS;
#pragma unroll
    for (int p = 0; p < PAIRS; ++p) {
        const float4 v = row[p ^ swz];   // steps 2p (v.x,v.y), 2p+1 (v.z,v.w)

        float ni = S * I * (v.x * INV_POP);
        float nr = v.y * I;
        S = S - ni;
        I = I + ni - nr;
        R = R + nr;

        ni = S * I * (v.z * INV_POP);
        nr = v.w * I;
        S = S - ni;
        I = I + ni - nr;
        R = R + nr;
    }
}

#define BAR()  __builtin_amdgcn_s_barrier()
#define LGKM0() asm volatile("s_waitcnt lgkmcnt(0)" ::: "memory")

__global__ __launch_bounds__(64 * (NPROD + 1))
void sir_scan_kernel(const float* __restrict__ in, const float* __restrict__ init,
                     float* __restrict__ out, int half)
{
    // 4 x 32 KB = 128 KB (1 block/CU), statically distinct objects
    __shared__ float4 buf0[BPB * PAIRS];
    __shared__ float4 buf1[BPB * PAIRS];
    __shared__ float4 buf2[BPB * PAIRS];
    __shared__ float4 buf3[BPB * PAIRS];

    const int tid = threadIdx.x;
    const int b0  = blockIdx.x * BPB;

    if (tid < 64) {
        // ---------------- consumer wave: zero outstanding VMEM in the loop
        const int gb = b0 + tid;
        float S = init[gb * 3 + 0];
        float I = init[gb * 3 + 1];
        float R = init[gb * 3 + 2];

        // BAR #c <=> "chunk c is in buf[c%4]" (producers drained lgkm first)
#pragma unroll 1
        for (int c = 0; c < NCHUNK; c += 4) {
            BAR(); compute_chunk(buf0, tid, S, I, R);
            BAR(); compute_chunk(buf1, tid, S, I, R);
            BAR(); compute_chunk(buf2, tid, S, I, R);
            BAR(); compute_chunk(buf3, tid, S, I, R);
        }

        out[gb * 3 + 0] = S;
        out[gb * 3 + 1] = I;
        out[gb * 3 + 2] = R;
        out[half + gb * 3 + 0] = S;
        out[half + gb * 3 + 1] = I;
        out[half + gb * 3 + 2] = R;
    } else {
        // ---------------- producer waves: reg-staged global->LDS
        const int lane = tid & 63;
        const int w    = (tid >> 6) - 1;   // 0..NPROD-1

        float4 ra[LPC], rb[LPC];           // fully-unrolled static indexing
        load_slice(in, b0, 0, w, lane, ra);
        load_slice(in, b0, 1, w, lane, rb);

        // Per phase: write chunk (compiler inserts minimal vmcnt(16) --
        // the other regset's 16 loads stay in flight), drain ds_writes,
        // barrier, issue next chunk's loads. Steady in-flight: 32 loads.
#pragma unroll 1
        for (int c = 0; c < NCHUNK; c += 4) {
            write_slice(buf0, w, lane, ra); LGKM0(); BAR();
            if (c + 2 < NCHUNK) load_slice(in, b0, c + 2, w, lane, ra);
            write_slice(buf1, w, lane, rb); LGKM0(); BAR();
            if (c + 3 < NCHUNK) load_slice(in, b0, c + 3, w, lane, rb);
            write_slice(buf2, w, lane, ra); LGKM0(); BAR();
            if (c + 4 < NCHUNK) load_slice(in, b0, c + 4, w, lane, ra);
            write_slice(buf3, w, lane, rb); LGKM0(); BAR();
            if (c + 5 < NCHUNK) load_slice(in, b0, c + 5, w, lane, rb);
        }
    }
}

extern "C" void kernel_launch(void* const* d_in, const int* in_sizes, int n_in,
                              void* d_out, int out_size, void* d_ws, size_t ws_size,
                              hipStream_t stream) {
    (void)in_sizes; (void)n_in; (void)d_ws; (void)ws_size;
    const float* in   = (const float*)d_in[0];   // (B, T, 2) fp32
    const float* init = (const float*)d_in[1];   // (B, 3)    fp32
    float* out        = (float*)d_out;           // 2 x (B, 3) fp32, concatenated
    const int half = out_size / 2;

    dim3 grid(16384 / BPB);          // 256 blocks, 1 per CU
    dim3 block(64 * (NPROD + 1));    // wave 0 consumer, waves 1-2 producers
    sir_scan_kernel<<<grid, block, 0, stream>>>(in, init, out, half);
}

// Round 6
// 60.811 us; speedup vs baseline: 1.8723x; 1.8723x over previous
//
#include <hip/hip_runtime.h>
#include <stdint.h>
#include <stddef.h>

// SIR scan: B=16384 batches, T=2048 steps, F=2 (beta,gamma), fp32.
// Round 6: test "per-wave outstanding-miss cap" theory.
// R3's producer/consumer pair is pinned at 7.6 B/cyc/CU (= ~53 lines in
// flight x 900cy HBM latency), with compute+latency fully hidden.
// This round: 512 blocks x 32 batches -- TWO fully independent R3 pairs
// per CU (own barriers, own buffers, no convoy coupling; LDS 64 KB/block
// forces exactly 2 blocks/CU). If miss tracking is per-wave, in-flight
// lines double -> chip read ceiling (~6.5 TB/s) -> ~42 us.

#define T_STEPS 2048
#define C_STEPS 64                   // timesteps per chunk
#define NCHUNK  (T_STEPS / C_STEPS)  // 32
#define BPB     32                   // batches per block
#define PAIRS   (C_STEPS / 2)        // 32 float4 slots per batch per chunk
#define IPC     16                   // global_load_lds instrs per 16 KB chunk

#define INV_POP 1e-6f

// Stage chunk c of this block's 32 batches into lds (linear dest,
// swizzle carried by the per-lane GLOBAL address -- rule #21).
// Instruction j covers rows {2j, 2j+1}: lane l -> row 2j + (l>>5),
// slot q = l&31, global pair p = q ^ (row&15).
__device__ __forceinline__ void stage_chunk(const float* __restrict__ in,
                                            float4* lds, int b0, int c, int lane)
{
    const int hi = lane >> 5;   // 0 or 1
    const int q  = lane & 31;
#pragma unroll
    for (int j = 0; j < IPC; ++j) {
        const int bi = 2 * j + hi;              // row within block (0..31)
        const int p  = q ^ (bi & 15);           // swizzled global pair index
        const float* g = in
            + (size_t)(b0 + bi) * (T_STEPS * 2)
            + (size_t)c * (C_STEPS * 2)
            + (size_t)(p * 4);
        float4* l = lds + j * 64;               // 1 KB per instruction, uniform
        __builtin_amdgcn_global_load_lds(
            (__attribute__((address_space(1))) void*)g,
            (__attribute__((address_space(3))) void*)l,
            16, 0, 0);
    }
}

// Consume one chunk: 32 ds_read_b128 per lane (XOR swizzle; 2 lanes per
// slot = same-address broadcast, free), 64 recurrence steps in time order.
__device__ __forceinline__ void compute_chunk(const float4* lds, int r,
                                              float& S, float& I, float& R)
{
    const int swz = r & 15;
    const float4* row = lds + r * PAIRS;
#pragma unroll
    for (int p = 0; p < PAIRS; ++p) {
        const float4 v = row[p ^ swz];   // steps 2p (v.x,v.y), 2p+1 (v.z,v.w)

        float ni = S * I * (v.x * INV_POP);
        float nr = v.y * I;
        S = S - ni;
        I = I + ni - nr;
        R = R + nr;

        ni = S * I * (v.z * INV_POP);
        nr = v.w * I;
        S = S - ni;
        I = I + ni - nr;
        R = R + nr;
    }
}

#define BAR()    asm volatile("s_barrier" ::: "memory")
#define WAIT16() asm volatile("s_waitcnt vmcnt(16)" ::: "memory")
#define WAIT0()  asm volatile("s_waitcnt vmcnt(0)"  ::: "memory")

__global__ __launch_bounds__(128)
void sir_scan_kernel(const float* __restrict__ in, const float* __restrict__ init,
                     float* __restrict__ out, int half)
{
    // 4 x 16 KB = 64 KB -> exactly 2 blocks/CU (LDS-bound packing)
    __shared__ float4 buf0[BPB * PAIRS];
    __shared__ float4 buf1[BPB * PAIRS];
    __shared__ float4 buf2[BPB * PAIRS];
    __shared__ float4 buf3[BPB * PAIRS];

    const int tid = threadIdx.x;
    const int b0  = blockIdx.x * BPB;

    if (tid < 64) {
        // ------------- consumer wave: zero outstanding VMEM in the loop.
        // Lanes >=32 duplicate lane (tid&31)'s work (no OOB, no divergence);
        // only lanes <32 store.
        const int r  = tid & 31;
        const int gb = b0 + r;
        float S = init[gb * 3 + 0];
        float I = init[gb * 3 + 1];
        float R = init[gb * 3 + 2];

        // BAR #c <=> "chunk c has landed" (producer waits vmcnt first)
#pragma unroll 1
        for (int c = 0; c < NCHUNK; c += 4) {
            BAR(); compute_chunk(buf0, r, S, I, R);
            BAR(); compute_chunk(buf1, r, S, I, R);
            BAR(); compute_chunk(buf2, r, S, I, R);
            BAR(); compute_chunk(buf3, r, S, I, R);
        }

        if (tid < 32) {
            out[gb * 3 + 0] = S;
            out[gb * 3 + 1] = I;
            out[gb * 3 + 2] = R;
            out[half + gb * 3 + 0] = S;
            out[half + gb * 3 + 1] = I;
            out[half + gb * 3 + 2] = R;
        }
    } else {
        // ------------- producer wave: all staging + counted waits here
        const int lane = tid - 64;

        stage_chunk(in, buf0, b0, 0, lane);
        stage_chunk(in, buf1, b0, 1, lane);

        // Invariant at each WAIT16: outstanding = chunks {c, c+1} (32
        // instrs); vmcnt(16) => chunk c fully landed, c+1 in flight.
        // After BAR #c we stage chunk c+2 into buf[(c+2)%4], which the
        // consumer finished two barriers ago (lockstep => WAR safe).
#pragma unroll 1
        for (int c = 0; c < NCHUNK - 4; c += 4) {
            WAIT16(); BAR(); stage_chunk(in, buf2, b0, c + 2, lane);
            WAIT16(); BAR(); stage_chunk(in, buf3, b0, c + 3, lane);
            WAIT16(); BAR(); stage_chunk(in, buf0, b0, c + 4, lane);
            WAIT16(); BAR(); stage_chunk(in, buf1, b0, c + 5, lane);
        }
        // chunks 28..31: stage only 30, 31
        WAIT16(); BAR(); stage_chunk(in, buf2, b0, NCHUNK - 2, lane);
        WAIT16(); BAR(); stage_chunk(in, buf3, b0, NCHUNK - 1, lane);
        WAIT16(); BAR();   // chunk 30 landed (outstanding {30,31})
        WAIT0();  BAR();   // chunk 31 landed
    }
}

extern "C" void kernel_launch(void* const* d_in, const int* in_sizes, int n_in,
                              void* d_out, int out_size, void* d_ws, size_t ws_size,
                              hipStream_t stream) {
    (void)in_sizes; (void)n_in; (void)d_ws; (void)ws_size;
    const float* in   = (const float*)d_in[0];   // (B, T, 2) fp32
    const float* init = (const float*)d_in[1];   // (B, 3)    fp32
    float* out        = (float*)d_out;           // 2 x (B, 3) fp32, concatenated
    const int half = out_size / 2;

    dim3 grid(16384 / BPB);   // 512 blocks -> exactly 2 per CU (LDS-bound)
    dim3 block(128);          // wave 0 = consumer, wave 1 = producer
    sir_scan_kernel<<<grid, block, 0, stream>>>(in, init, out, half);
}